// Round 4
// baseline (781.674 us; speedup 1.0000x reference)
//
#include <hip/hip_runtime.h>

// Side Window Filter — bit-exact vs harness np ref (absmax 0.0 contract).
// Math contract (DO NOT REORDER): per output, each of the 8 windows is a
// sequential __builtin_fmaf chain over its taps in row-major (i,j) order,
// fp32 accumulator starting at 0, weights fp32(1/15), fp32(1/9); replicate
// boundary; 8 iterations; fp32 iterates; fp32 d/argmin(first-idx)/update;
// final clip(|x0-res|,0,255).
//
// R14: pair-processing. R13 post-mortem: LDS port time (~24us) ~= VALU
// time (~29us) per dispatch and they serialize at low warp depth. Output
// rows t and t+1 share 4 of their 5 window rows, so we walk the 6-row
// union ONCE (i=0..5), feeding phase i of row-t and phase i-1 of row-t+1
// from the same 20 just-read floats. 15 b128/output-row instead of 25
// -> LDS port ~14us, and each read feeds 2x the fmas. Each accumulator
// still sees its rows in exact row-major order -> bit-exact (independent
// fp32 chains interleaved, never reordered). 1-wave blocks, RPT=8
// (4 pairs, rolled), LDS 13.2 KB -> 12 blocks/CU, launch_bounds(64,3).

static constexpr int H     = 2048;
static constexpr int W     = 2048;
static constexpr int C     = 3;
static constexpr int WC    = W * C;        // 6144 floats per row
static constexpr int RPT   = 8;            // output rows per block (4 pairs)
static constexpr int TPB   = 64;           // one wave per block
static constexpr int BCOLS = TPB * 4;      // 256 output floats per block
static constexpr int RW    = BCOLS + 20;   // 276 staged floats per row
static constexpr int NROWS = RPT + 4;      // 12 staged rows
static constexpr int NCH   = RW / 4;       // 69 float4 chunks per row
static constexpr int NBX   = WC / BCOLS;   // 24 x-blocks

// One window-row phase of the 8 directional chains for one output column.
// ph is compile-time constant at every call site (unrolled i-loop) so the
// branches fold away. Chain statement order is IDENTICAL to the verified
// R10/R13 kernels — do not reorder.
__device__ __forceinline__ void apply_phase(float* __restrict__ a,
                                            const float* __restrict__ r,
                                            int k, int ph, float& center,
                                            float w15, float w9) {
  const float t0 = r[k+2], t1 = r[k+5], t2 = r[k+8],
              t3 = r[k+11], t4 = r[k+14];
  if (ph == 2) center = t2;
  // L: cols 0..2, all rows
  a[0]=__builtin_fmaf(w15,t0,a[0]); a[0]=__builtin_fmaf(w15,t1,a[0]); a[0]=__builtin_fmaf(w15,t2,a[0]);
  // R: cols 2..4, all rows
  a[1]=__builtin_fmaf(w15,t2,a[1]); a[1]=__builtin_fmaf(w15,t3,a[1]); a[1]=__builtin_fmaf(w15,t4,a[1]);
  if (ph <= 2) {  // U: rows 0..2, all cols
    a[2]=__builtin_fmaf(w15,t0,a[2]); a[2]=__builtin_fmaf(w15,t1,a[2]); a[2]=__builtin_fmaf(w15,t2,a[2]);
    a[2]=__builtin_fmaf(w15,t3,a[2]); a[2]=__builtin_fmaf(w15,t4,a[2]);
    // NW / NE
    a[4]=__builtin_fmaf(w9,t0,a[4]); a[4]=__builtin_fmaf(w9,t1,a[4]); a[4]=__builtin_fmaf(w9,t2,a[4]);
    a[5]=__builtin_fmaf(w9,t2,a[5]); a[5]=__builtin_fmaf(w9,t3,a[5]); a[5]=__builtin_fmaf(w9,t4,a[5]);
  }
  if (ph >= 2) {  // D: rows 2..4, all cols
    a[3]=__builtin_fmaf(w15,t0,a[3]); a[3]=__builtin_fmaf(w15,t1,a[3]); a[3]=__builtin_fmaf(w15,t2,a[3]);
    a[3]=__builtin_fmaf(w15,t3,a[3]); a[3]=__builtin_fmaf(w15,t4,a[3]);
    // SW / SE
    a[6]=__builtin_fmaf(w9,t0,a[6]); a[6]=__builtin_fmaf(w9,t1,a[6]); a[6]=__builtin_fmaf(w9,t2,a[6]);
    a[7]=__builtin_fmaf(w9,t2,a[7]); a[7]=__builtin_fmaf(w9,t3,a[7]); a[7]=__builtin_fmaf(w9,t4,a[7]);
  }
}

// fp32 d/argmin/update epilogue for one output column (order-contractual).
__device__ __forceinline__ float finish(const float* __restrict__ a,
                                        float center) {
  float best  = a[0] - center;
  float besta = fabsf(best);
#pragma unroll
  for (int m = 1; m < 8; ++m) {
    const float d  = a[m] - center;
    const float ab = fabsf(d);
    if (ab < besta) { besta = ab; best = d; }
  }
  return center + best;
}

template<bool FINAL>
__global__ __launch_bounds__(TPB, 3)
void swf_pair(const float* __restrict__ src, float* __restrict__ dst,
              const float* __restrict__ x0) {
  __shared__ __align__(16) float s[NROWS][RW];

  const int tid  = threadIdx.x;
  const int bx   = blockIdx.x;
  const int y0   = blockIdx.y * RPT;
  const int base = bx * BCOLS - 8;       // global float idx of LDS col 0

  // interior iff every staged float of this block is in [0, WC)
  const bool interior = (bx >= 1) && (bx <= NBX - 2);

  // ---- stage 12 rows (vertical replicate via hy clamp; horizontal
  //      replicate folded into halo values) ----
#pragma unroll 1
  for (int r = 0; r < NROWS; ++r) {
    int hy = y0 + r - 2;
    hy = hy < 0 ? 0 : (hy > H - 1 ? H - 1 : hy);
    const float* srow = src + (size_t)hy * WC;
    if (interior) {
      const float4 va = *(const float4*)(srow + base + tid * 4);
      *(float4*)&s[r][tid * 4] = va;
      if (tid < NCH - 64) {
        const float4 vb = *(const float4*)(srow + base + (tid + 64) * 4);
        *(float4*)&s[r][(tid + 64) * 4] = vb;
      }
    } else {
#pragma unroll 1
      for (int cc = tid; cc < NCH; cc += TPB) {
        const int gp = base + cc * 4;
        float tmp[4];
#pragma unroll
        for (int u = 0; u < 4; ++u) {
          const int f = gp + u;
          const int idx = (f < 0)    ? ((f % 3) + 3) % 3
                        : (f >= WC)  ? (W - 1) * 3 + (f % 3)
                        : f;
          tmp[u] = srow[idx];
        }
        float4 v; v.x = tmp[0]; v.y = tmp[1]; v.z = tmp[2]; v.w = tmp[3];
        *(float4*)&s[r][cc * 4] = v;
      }
    }
  }
  __syncthreads();

  const float w15 = 1.0f / 15.0f;   // fp32(1/15)
  const float w9  = 1.0f / 9.0f;    // fp32(1/9)
  const int   lc   = tid * 4;               // LDS float idx of window start
  const int   col4 = bx * BCOLS + tid * 4;  // global output float idx

#pragma unroll 1
  for (int pr = 0; pr < RPT / 2; ++pr) {
    const int t = pr * 2;           // output rows y0+t (A) and y0+t+1 (B)

    float accA[4][8], accB[4][8];
#pragma unroll
    for (int k = 0; k < 4; ++k)
#pragma unroll
      for (int m = 0; m < 8; ++m) { accA[k][m] = 0.0f; accB[k][m] = 0.0f; }
    float centerA[4], centerB[4];

    // walk the 6-row union: row t+i feeds phase i of A (i<=4) and
    // phase i-1 of B (i>=1)
#pragma unroll
    for (int i = 0; i < 6; ++i) {
      const float* row = &s[t + i][lc];
      const float4 q0 = *(const float4*)(row);
      const float4 q1 = *(const float4*)(row + 4);
      const float4 q2 = *(const float4*)(row + 8);
      const float4 q3 = *(const float4*)(row + 12);
      const float4 q4 = *(const float4*)(row + 16);
      const float r[20] = {q0.x,q0.y,q0.z,q0.w, q1.x,q1.y,q1.z,q1.w,
                           q2.x,q2.y,q2.z,q2.w, q3.x,q3.y,q3.z,q3.w,
                           q4.x,q4.y,q4.z,q4.w};
#pragma unroll
      for (int k = 0; k < 4; ++k) {
        if (i <= 4) apply_phase(accA[k], r, k, i,     centerA[k], w15, w9);
        if (i >= 1) apply_phase(accB[k], r, k, i - 1, centerB[k], w15, w9);
      }
    }

    // epilogue: two output rows, float4 stores
#pragma unroll
    for (int half = 0; half < 2; ++half) {
      const int   y  = y0 + t + half;
      const float* c = half ? centerB : centerA;
      float4 xv4;
      if (FINAL) xv4 = *(const float4*)(x0 + (size_t)y * WC + col4);
      float o[4];
#pragma unroll
      for (int k = 0; k < 4; ++k) {
        const float res = finish(half ? accB[k] : accA[k], c[k]);
        if (FINAL) {
          const float xv = (k == 0) ? xv4.x : (k == 1) ? xv4.y
                         : (k == 2) ? xv4.z : xv4.w;
          float diff = fabsf(xv - res);
          o[k] = diff > 255.0f ? 255.0f : diff;
        } else {
          o[k] = res;
        }
      }
      float4 ov;
      ov.x = o[0]; ov.y = o[1]; ov.z = o[2]; ov.w = o[3];
      *(float4*)(dst + (size_t)y * WC + col4) = ov;
    }
  }
}

extern "C" void kernel_launch(void* const* d_in, const int* in_sizes, int n_in,
                              void* d_out, int out_size, void* d_ws, size_t ws_size,
                              hipStream_t stream) {
  const float* x0  = (const float*)d_in[0];
  float*       out = (float*)d_out;
  float*       ws  = (float*)d_ws;   // needs H*W*C*4 = 50.3 MB

  dim3 grid(NBX, H / RPT);           // 24 x-blocks, 256 y-blocks
  dim3 block(TPB);

  swf_pair<false><<<grid, block, 0, stream>>>(x0,  ws,  nullptr);  // iter 1
  swf_pair<false><<<grid, block, 0, stream>>>(ws,  out, nullptr);  // iter 2
  swf_pair<false><<<grid, block, 0, stream>>>(out, ws,  nullptr);  // iter 3
  swf_pair<false><<<grid, block, 0, stream>>>(ws,  out, nullptr);  // iter 4
  swf_pair<false><<<grid, block, 0, stream>>>(out, ws,  nullptr);  // iter 5
  swf_pair<false><<<grid, block, 0, stream>>>(ws,  out, nullptr);  // iter 6
  swf_pair<false><<<grid, block, 0, stream>>>(out, ws,  nullptr);  // iter 7
  swf_pair<true ><<<grid, block, 0, stream>>>(ws,  out, x0);       // iter 8 + diff
}

// Round 5
// 458.777 us; speedup vs baseline: 1.7038x; 1.7038x over previous
//
#include <hip/hip_runtime.h>

// Side Window Filter — bit-exact vs harness np ref (absmax 0.0 contract).
// Math contract (DO NOT REORDER): per output, each of the 8 windows is a
// sequential __builtin_fmaf chain over its taps in row-major (i,j) order,
// fp32 accumulator starting at 0, weights fp32(1/15), fp32(1/9); replicate
// boundary; 8 iterations; fp32 iterates; fp32 d/argmin(first-idx)/update;
// final clip(|x0-res|,0,255).
//
// R15: pair-processing with FLAT GLOBAL loads (no LDS, no barrier) and a
// PINNED register budget. R14 post-mortem: launch_bounds(64,3) is only a
// floor — the allocator targeted ~6 waves/EU (VGPR 84) and spilled 92 MB
// of accumulators to scratch (WRITE_SIZE 49->142 MB). Here
// amdgpu_waves_per_eu(3,3) pins the budget at ~170 VGPR so the ~115 live
// floats (2x32 acc + 20-float window + addressing) stay in registers.
// Each thread computes output rows (2y, 2y+1) for its 4 columns by
// walking the 6-row window union once: row i feeds phase i of row A
// (i<=4) and phase i-1 of row B (i>=1) from the same 5 float4 loads.
// 15 loads/output-row vs R10's 25; L1 serves the wave-overlapping
// slices. Each acc chain still sees its taps in exact row-major order
// -> bit-exact (independent fp32 chains, interleaved but never reordered).

static constexpr int H  = 2048;
static constexpr int W  = 2048;
static constexpr int C  = 3;
static constexpr int WC = W * C;   // 6144 floats per row

// One window-row phase of the 8 directional chains for one output column.
// ph is compile-time at every call site (unrolled loops) so branches fold.
// Chain statement order is IDENTICAL to the verified R10/R13 kernels.
__device__ __forceinline__ void apply_phase_t(float* __restrict__ a,
                                              float t0, float t1, float t2,
                                              float t3, float t4,
                                              int ph, float& center,
                                              float w15, float w9) {
  if (ph == 2) center = t2;
  // L: cols 0..2, all rows
  a[0]=__builtin_fmaf(w15,t0,a[0]); a[0]=__builtin_fmaf(w15,t1,a[0]); a[0]=__builtin_fmaf(w15,t2,a[0]);
  // R: cols 2..4, all rows
  a[1]=__builtin_fmaf(w15,t2,a[1]); a[1]=__builtin_fmaf(w15,t3,a[1]); a[1]=__builtin_fmaf(w15,t4,a[1]);
  if (ph <= 2) {  // U: rows 0..2, all cols
    a[2]=__builtin_fmaf(w15,t0,a[2]); a[2]=__builtin_fmaf(w15,t1,a[2]); a[2]=__builtin_fmaf(w15,t2,a[2]);
    a[2]=__builtin_fmaf(w15,t3,a[2]); a[2]=__builtin_fmaf(w15,t4,a[2]);
    // NW / NE
    a[4]=__builtin_fmaf(w9,t0,a[4]); a[4]=__builtin_fmaf(w9,t1,a[4]); a[4]=__builtin_fmaf(w9,t2,a[4]);
    a[5]=__builtin_fmaf(w9,t2,a[5]); a[5]=__builtin_fmaf(w9,t3,a[5]); a[5]=__builtin_fmaf(w9,t4,a[5]);
  }
  if (ph >= 2) {  // D: rows 2..4, all cols
    a[3]=__builtin_fmaf(w15,t0,a[3]); a[3]=__builtin_fmaf(w15,t1,a[3]); a[3]=__builtin_fmaf(w15,t2,a[3]);
    a[3]=__builtin_fmaf(w15,t3,a[3]); a[3]=__builtin_fmaf(w15,t4,a[3]);
    // SW / SE
    a[6]=__builtin_fmaf(w9,t0,a[6]); a[6]=__builtin_fmaf(w9,t1,a[6]); a[6]=__builtin_fmaf(w9,t2,a[6]);
    a[7]=__builtin_fmaf(w9,t2,a[7]); a[7]=__builtin_fmaf(w9,t3,a[7]); a[7]=__builtin_fmaf(w9,t4,a[7]);
  }
}

// fp32 d/argmin/update epilogue for one output column (order-contractual).
__device__ __forceinline__ float finish(const float* __restrict__ a,
                                        float center) {
  float best  = a[0] - center;
  float besta = fabsf(best);
#pragma unroll
  for (int m = 1; m < 8; ++m) {
    const float d  = a[m] - center;
    const float ab = fabsf(d);
    if (ab < besta) { besta = ab; best = d; }
  }
  return center + best;
}

template<bool FINAL>
__global__ __attribute__((amdgpu_waves_per_eu(3, 3))) __launch_bounds__(256)
void swf_pg(const float* __restrict__ src, float* __restrict__ dst,
            const float* __restrict__ x0) {
  const int col4 = (blockIdx.x * 256 + threadIdx.x) * 4;  // 16B-aligned
  const int yA   = blockIdx.y * 2;                        // rows yA, yA+1

  const float w15 = 1.0f / 15.0f;   // fp32(1/15)
  const float w9  = 1.0f / 9.0f;    // fp32(1/9)

  float accA[4][8], accB[4][8];
#pragma unroll
  for (int k = 0; k < 4; ++k)
#pragma unroll
    for (int m = 0; m < 8; ++m) { accA[k][m] = 0.0f; accB[k][m] = 0.0f; }
  float centerA[4], centerB[4];

  // fast iff all taps for cols col4..col4+3 lie in [col4-8, col4+12)
  const bool fastc = (col4 >= 8) && (col4 <= WC - 12);
  if (fastc) {
    const float* colbase = src + (col4 - 8);
    // walk the 6-row union: row yA+i-2 feeds phase i of A (i<=4) and
    // phase i-1 of B (i>=1)
#pragma unroll
    for (int i = 0; i < 6; ++i) {
      int hy = yA + i - 2;
      hy = hy < 0 ? 0 : (hy > H - 1 ? H - 1 : hy);     // replicate rows
      const float4* rp = (const float4*)(colbase + (size_t)hy * WC);
      const float4 q0 = rp[0], q1 = rp[1], q2 = rp[2], q3 = rp[3], q4 = rp[4];
      const float r[20] = {q0.x,q0.y,q0.z,q0.w, q1.x,q1.y,q1.z,q1.w,
                           q2.x,q2.y,q2.z,q2.w, q3.x,q3.y,q3.z,q3.w,
                           q4.x,q4.y,q4.z,q4.w};
#pragma unroll
      for (int k = 0; k < 4; ++k) {
        // tap j of output col4+k -> r[k + 3j + 2]
        const float t0 = r[k+2], t1 = r[k+5], t2 = r[k+8],
                    t3 = r[k+11], t4 = r[k+14];
        if (i <= 4) apply_phase_t(accA[k], t0,t1,t2,t3,t4, i,     centerA[k], w15, w9);
        if (i >= 1) apply_phase_t(accB[k], t0,t1,t2,t3,t4, i - 1, centerB[k], w15, w9);
      }
    }
  } else {
    // edge columns (col4 in {0,4,WC-8,WC-4}): scalar clamped gather,
    // identical chain structure; column clamps hoisted (row-invariant)
    int cjk[4][5];
#pragma unroll
    for (int k = 0; k < 4; ++k) {
      const int col = col4 + k;
      const int w   = col / 3;
      const int c   = col - w * 3;
#pragma unroll
      for (int j = 0; j < 5; ++j) {
        int wj = w + j - 2;
        wj = wj < 0 ? 0 : (wj > W - 1 ? W - 1 : wj);   // replicate cols
        cjk[k][j] = wj * 3 + c;
      }
    }
#pragma unroll
    for (int i = 0; i < 6; ++i) {
      int hy = yA + i - 2;
      hy = hy < 0 ? 0 : (hy > H - 1 ? H - 1 : hy);
      const float* rr = src + (size_t)hy * WC;
#pragma unroll
      for (int k = 0; k < 4; ++k) {
        const float t0 = rr[cjk[k][0]], t1 = rr[cjk[k][1]], t2 = rr[cjk[k][2]],
                    t3 = rr[cjk[k][3]], t4 = rr[cjk[k][4]];
        if (i <= 4) apply_phase_t(accA[k], t0,t1,t2,t3,t4, i,     centerA[k], w15, w9);
        if (i >= 1) apply_phase_t(accB[k], t0,t1,t2,t3,t4, i - 1, centerB[k], w15, w9);
      }
    }
  }

  // epilogue: two output rows, fp32 d/argmin/update, float4 stores
#pragma unroll
  for (int half = 0; half < 2; ++half) {
    const int y = yA + half;
    float4 xv4;
    if (FINAL) xv4 = *(const float4*)(x0 + (size_t)y * WC + col4);
    float o[4];
#pragma unroll
    for (int k = 0; k < 4; ++k) {
      const float res = half ? finish(accB[k], centerB[k])
                             : finish(accA[k], centerA[k]);
      if (FINAL) {
        const float xv = (k == 0) ? xv4.x : (k == 1) ? xv4.y
                       : (k == 2) ? xv4.z : xv4.w;
        float diff = fabsf(xv - res);
        o[k] = diff > 255.0f ? 255.0f : diff;
      } else {
        o[k] = res;
      }
    }
    float4 ov;
    ov.x = o[0]; ov.y = o[1]; ov.z = o[2]; ov.w = o[3];
    *(float4*)(dst + (size_t)y * WC + col4) = ov;
  }
}

extern "C" void kernel_launch(void* const* d_in, const int* in_sizes, int n_in,
                              void* d_out, int out_size, void* d_ws, size_t ws_size,
                              hipStream_t stream) {
  const float* x0  = (const float*)d_in[0];
  float*       out = (float*)d_out;
  float*       ws  = (float*)d_ws;   // needs H*W*C*4 = 50.3 MB

  dim3 grid(WC / 1024, H / 2);       // 6 x-blocks (256 thr x 4 cols), 1024 row-pairs
  dim3 block(256);

  swf_pg<false><<<grid, block, 0, stream>>>(x0,  ws,  nullptr);  // iter 1
  swf_pg<false><<<grid, block, 0, stream>>>(ws,  out, nullptr);  // iter 2
  swf_pg<false><<<grid, block, 0, stream>>>(out, ws,  nullptr);  // iter 3
  swf_pg<false><<<grid, block, 0, stream>>>(ws,  out, nullptr);  // iter 4
  swf_pg<false><<<grid, block, 0, stream>>>(out, ws,  nullptr);  // iter 5
  swf_pg<false><<<grid, block, 0, stream>>>(ws,  out, nullptr);  // iter 6
  swf_pg<false><<<grid, block, 0, stream>>>(out, ws,  nullptr);  // iter 7
  swf_pg<true ><<<grid, block, 0, stream>>>(ws,  out, x0);       // iter 8 + diff
}